// Round 11
// baseline (40.861 us; speedup 1.0000x reference)
//
#include <hip/hip_runtime.h>
#include <math.h>

#define NUM_CLASSES 80
#define OBJ_BLOCKS 48                   // 3 scales x 16 batches
#define NEG0_BLOCKS 75                  // 76800 float4 / 1024 (exact)
#define NEG1_BLOCKS 19                  // ceil(19200 / 1024)
#define NEG2_BLOCKS 5                   // ceil(4800 / 1024)
#define NEG_BLOCKS (NEG0_BLOCKS + NEG1_BLOCKS + NEG2_BLOCKS)   // 99
#define TOTAL_BLOCKS (OBJ_BLOCKS + NEG_BLOCKS + 1)             // 148
#define NEG_BASE (OBJ_BLOCKS * 8)       // = 384 floats

// ---- math helpers (match jax.nn.log_sigmoid / sigmoid in f32) ----
__device__ __forceinline__ float softplusf_(float x) {
    return x > 0.f ? x + log1pf(expf(-x)) : log1pf(expf(x));
}
__device__ __forceinline__ float sigmoidf_(float x) {
    return 1.f / (1.f + expf(-x));
}
// focal_bce(x, t=0) = softplus(x) * sigmoid(x)^2   (strictly > 0 for finite x)
__device__ __forceinline__ float focal0(float x) {
    float s = sigmoidf_(x);
    return softplusf_(x) * s * s;
}
// focal_bce(x, t=1) = softplus(-x) * sigmoid(-x)^2
__device__ __forceinline__ float focal1(float x) {
    float s = sigmoidf_(-x);
    return softplusf_(-x) * s * s;
}

// agent-scope RELAXED atomics (sc1 => LLC-coherent across XCDs). NO release/
// acquire: R9 proved agent-release costs an L2 writeback per block. Producer
// orders data-before-flag with `s_waitcnt vmcnt(0)` (own stores only, R10 OK).
__device__ __forceinline__ void st_ws(float* p, float v) {
    __hip_atomic_store(p, v, __ATOMIC_RELAXED, __HIP_MEMORY_SCOPE_AGENT);
}
__device__ __forceinline__ float ld_ws(const float* p) {
    return __hip_atomic_load(p, __ATOMIC_RELAXED, __HIP_MEMORY_SCOPE_AGENT);
}

// ws layout (floats), 48*8 + 99 = 483 total:
//   [sb*8 .. +5]    obj data: [0]=xy [1]=wh [2]=cls [3]=pos [4]=neg_corr [5]=n_obj
//   [sb*8 + 6]      obj flag: ==1.0f when written (reset to -1.0f each call)
//   [NEG_BASE + q]  neg partial; strictly > 0 when written => self-flagging
// First call: 0x00/0xAA poison fails both ==1.0f and >0.0f tests.

template<int NI, int PLANE4>
__device__ __forceinline__ float neg_sum(const float* __restrict__ P,
                                         int lq, int tid) {
    float sum = 0.f;
    #pragma unroll
    for (int k = 0; k < 4; ++k) {
        const int idx = lq * 1024 + k * 256 + tid;
        if (idx < NI) {
            const int plane = idx / PLANE4;          // compile-time divisor
            const int r4 = idx - plane * PLANE4;
            const int b = plane / 3;
            const int a = plane - b * 3;
            const float4 v = *reinterpret_cast<const float4*>(
                P + (size_t)(b * 255 + a * 85 + 4) * (PLANE4 * 4)
                  + (size_t)r4 * 4);
            sum += focal0(v.x) + focal0(v.y) + focal0(v.z) + focal0(v.w);
        }
    }
    return sum;
}

__global__ __launch_bounds__(256)
void fused_kernel(const float* __restrict__ p0,
                  const float* __restrict__ p1,
                  const float* __restrict__ p2,
                  const float* __restrict__ tgt,
                  float* __restrict__ ws,
                  float* __restrict__ out) {
    __shared__ int      s_cell[32];     // per-target cell (-1 invalid)
    __shared__ int      s_off[32];      // channel-0 offset within batch slab
    __shared__ int      s_win[32];      // winner flag
    __shared__ float    s_geo[32][4];   // tx, ty, tw_target, th_target
    __shared__ unsigned s_um[32][3];    // class-union bitmask
    __shared__ float    s_nwin;
    __shared__ float    s_red[4][5];    // per-wave partial sums
    __shared__ float    s_nred[4][3];
    __shared__ float    s_obj[3][6];

    const int bid = blockIdx.x;
    const int tid = threadIdx.x;        // 256 threads = 4 waves
    const int lane = tid & 63;
    const int wid  = tid >> 6;

    if (bid < OBJ_BLOCKS) {
        // ============ object path: one block per (scale, batch) ============
        const int s = bid >> 4;          // /16
        const int b = bid & 15;
        const int H  = (s == 0) ? 80 : (s == 1 ? 40 : 20);
        const int W  = H;
        const int HW = H * W;

        float aw0, aw1, aw2, ah0, ah1, ah2;
        if (s == 0) { aw0=10.f/640.f; aw1=16.f/640.f; aw2=33.f/640.f;
                      ah0=13.f/640.f; ah1=30.f/640.f; ah2=23.f/640.f; }
        else if (s == 1) { aw0=30.f/640.f; aw1=62.f/640.f; aw2=59.f/640.f;
                           ah0=61.f/640.f; ah1=45.f/640.f; ah2=119.f/640.f; }
        else { aw0=116.f/640.f; aw1=156.f/640.f; aw2=373.f/640.f;
               ah0=90.f/640.f;  ah1=198.f/640.f; ah2=326.f/640.f; }

        // Phase 1: per-target cell + geometry (threads 0..31, wave 0)
        int   myCls = 0;
        if (tid < 32) {
            const float* tg = tgt + (size_t)(b * 32 + tid) * 5;
            const float w = tg[3], h = tg[4];
            myCls = (int)tg[0];
            int cell = -1, off = 0;
            float g0 = 0.f, g1 = 0.f, g2 = 0.f, g3 = 0.f;
            if (w > 0.f && h > 0.f) {
                // argmax IoU over 3 anchors, first-max on ties (strict >)
                float best = -1.f; int ba = 0;
                float inter = fminf(w, aw0) * fminf(h, ah0);
                float iou = inter / (w * h + aw0 * ah0 - inter + 1e-6f);
                if (iou > best) { best = iou; ba = 0; }
                inter = fminf(w, aw1) * fminf(h, ah1);
                iou = inter / (w * h + aw1 * ah1 - inter + 1e-6f);
                if (iou > best) { best = iou; ba = 1; }
                inter = fminf(w, aw2) * fminf(h, ah2);
                iou = inter / (w * h + aw2 * ah2 - inter + 1e-6f);
                if (iou > best) { best = iou; ba = 2; }
                const float aw = (ba == 0) ? aw0 : (ba == 1 ? aw1 : aw2);
                const float ah = (ba == 0) ? ah0 : (ba == 1 ? ah1 : ah2);
                const float xw = tg[1] * (float)W, yh = tg[2] * (float)H;
                int gi = (int)xw; gi = min(max(gi, 0), W - 1); // trunc==astype(i32)
                int gj = (int)yh; gj = min(max(gj, 0), H - 1);
                cell = (ba * H + gj) * W + gi;
                off  = ba * 85 * HW + gj * W + gi;
                g0 = xw - (float)gi;
                g1 = yh - (float)gj;
                g2 = logf(w / aw + 1e-6f);
                g3 = logf(h / ah + 1e-6f);
            }
            s_cell[tid] = cell;
            s_off[tid]  = off;
            s_geo[tid][0] = g0; s_geo[tid][1] = g1;
            s_geo[tid][2] = g2; s_geo[tid][3] = g3;
        }
        __syncthreads();

        // Phase 2: winners (last-write-wins in t order) + class unions
        if (tid < 64) {                  // wave 0 only (needs ballot)
            bool winner = false;
            if (tid < 32) {
                const int mycell = s_cell[tid];
                winner = (mycell >= 0);
                if (winner) {
                    #pragma unroll 1
                    for (int t2 = tid + 1; t2 < 32; ++t2)
                        if (s_cell[t2] == mycell) { winner = false; break; }
                }
                unsigned um0 = 0, um1 = 0, um2 = 0;
                if (winner) {
                    // class UNION over all targets hitting this cell; need
                    // every colliding target's class -> gather via shuffle
                    #pragma unroll 1
                    for (int t2 = 0; t2 < 32; ++t2) {
                        if (s_cell[t2] == mycell) {
                            const int c = __shfl(myCls, t2, 64);
                            if (c < 32)      um0 |= 1u << c;
                            else if (c < 64) um1 |= 1u << (c - 32);
                            else             um2 |= 1u << (c - 64);
                        }
                    }
                }
                s_win[tid] = winner ? 1 : 0;
                s_um[tid][0] = um0; s_um[tid][1] = um1; s_um[tid][2] = um2;
            }
            const unsigned long long bal = __ballot(winner);
            if (tid == 0) s_nwin = (float)__popcll(bal);
        }
        __syncthreads();

        // Phase 3: 32 targets x 85 channels strided over 256 threads
        const float* Pb = ((s == 0) ? p0 : (s == 1 ? p1 : p2))
                          + (size_t)b * 255 * HW;
        float a0 = 0.f, a1 = 0.f, a2 = 0.f, a3 = 0.f, a4 = 0.f;
        #pragma unroll 1
        for (int idx = tid; idx < 32 * 85; idx += 256) {
            const int t = idx / 85;
            const int f = idx - t * 85;
            if (!s_win[t]) continue;
            const float val = Pb[(size_t)s_off[t] + (size_t)f * HW];
            if (f == 0) {
                const float d = sigmoidf_(val) - s_geo[t][0];
                a0 += d * d;
            } else if (f == 1) {
                const float d = sigmoidf_(val) - s_geo[t][1];
                a0 += d * d;
            } else if (f == 2) {
                const float e = val - s_geo[t][2];
                a1 += e * e;
            } else if (f == 3) {
                const float e = val - s_geo[t][3];
                a1 += e * e;
            } else if (f == 4) {
                a3 += focal1(val);
                a4 -= focal0(val);       // correction to all-cell neg sum
            } else {
                const int c = f - 5;
                const bool ts = (c < 32) ? ((s_um[t][0] >> c) & 1)
                              : (c < 64) ? ((s_um[t][1] >> (c - 32)) & 1)
                                         : ((s_um[t][2] >> (c - 64)) & 1);
                a2 += ts ? focal1(val) : focal0(val);
            }
        }
        // block reduce 5 sums
        #pragma unroll
        for (int off = 32; off; off >>= 1) {
            a0 += __shfl_down(a0, off, 64); a1 += __shfl_down(a1, off, 64);
            a2 += __shfl_down(a2, off, 64); a3 += __shfl_down(a3, off, 64);
            a4 += __shfl_down(a4, off, 64);
        }
        if (lane == 0) {
            s_red[wid][0] = a0; s_red[wid][1] = a1; s_red[wid][2] = a2;
            s_red[wid][3] = a3; s_red[wid][4] = a4;
        }
        __syncthreads();
        if (tid == 0) {
            float* slot = ws + (size_t)bid * 8;
            #pragma unroll
            for (int k = 0; k < 5; ++k)
                st_ws(slot + k, s_red[0][k] + s_red[1][k]
                              + s_red[2][k] + s_red[3][k]);
            st_ws(slot + 5, s_nwin);
            asm volatile("s_waitcnt vmcnt(0)" ::: "memory");
            st_ws(slot + 6, 1.0f);                   // flag
        }
    } else if (bid < OBJ_BLOCKS + NEG_BLOCKS) {
        // ================= all-cell negative path =================
        const int q = bid - OBJ_BLOCKS;              // 0..98
        float sum;
        if (q < NEG0_BLOCKS)
            sum = neg_sum<76800, 1600>(p0, q, tid);
        else if (q < NEG0_BLOCKS + NEG1_BLOCKS)
            sum = neg_sum<19200, 400>(p1, q - NEG0_BLOCKS, tid);
        else
            sum = neg_sum<4800, 100>(p2, q - NEG0_BLOCKS - NEG1_BLOCKS, tid);
        #pragma unroll
        for (int off = 32; off; off >>= 1) sum += __shfl_down(sum, off, 64);
        if (lane == 0) s_red[wid][0] = sum;
        __syncthreads();
        // strictly positive value IS the flag; single word -> no ordering needed
        if (tid == 0)
            st_ws(ws + NEG_BASE + q,
                  s_red[0][0] + s_red[1][0] + s_red[2][0] + s_red[3][0]);
    } else {
        // ================= finalizer block =================
        // Producers never wait on anyone -> no circular wait. 148 blocks
        // co-resident trivially.
        // Phase A: one flag word per thread, single poll round per sweep.
        if (tid < OBJ_BLOCKS) {
            const float* fp = ws + (size_t)tid * 8 + 6;
            while (ld_ws(fp) != 1.0f) __builtin_amdgcn_s_sleep(1);
        } else if (tid < OBJ_BLOCKS + NEG_BLOCKS) {
            const float* np = ws + NEG_BASE + (tid - OBJ_BLOCKS);
            while (!(ld_ws(np) > 0.0f)) __builtin_amdgcn_s_sleep(1);
        }
        __syncthreads();

        // neg partials -> per-scale sums (threads 0..98 hold one each)
        {
            float v = (tid < NEG_BLOCKS) ? ld_ws(ws + NEG_BASE + tid) : 0.f;
            float n0 = (tid < NEG0_BLOCKS) ? v : 0.f;
            float n1 = (tid >= NEG0_BLOCKS && tid < NEG0_BLOCKS + NEG1_BLOCKS)
                       ? v : 0.f;
            float n2 = (tid >= NEG0_BLOCKS + NEG1_BLOCKS && tid < NEG_BLOCKS)
                       ? v : 0.f;
            #pragma unroll
            for (int off = 32; off; off >>= 1) {
                n0 += __shfl_down(n0, off, 64);
                n1 += __shfl_down(n1, off, 64);
                n2 += __shfl_down(n2, off, 64);
            }
            if (lane == 0) {
                s_nred[wid][0] = n0; s_nred[wid][1] = n1; s_nred[wid][2] = n2;
            }
        }

        // obj slots: thread i<48 loads slot i; 16-lane-group reduce per scale
        {
            float o[6];
            #pragma unroll
            for (int k = 0; k < 6; ++k)
                o[k] = (tid < OBJ_BLOCKS) ? ld_ws(ws + (size_t)tid * 8 + k) : 0.f;
            #pragma unroll
            for (int m = 8; m; m >>= 1)
                #pragma unroll
                for (int k = 0; k < 6; ++k) o[k] += __shfl_xor(o[k], m, 16);
            if (tid == 0 || tid == 16 || tid == 32) {
                #pragma unroll
                for (int k = 0; k < 6; ++k) s_obj[tid >> 4][k] = o[k];
            }
        }
        __syncthreads();

        if (tid == 0) {
            float total = 0.f;
            #pragma unroll 1
            for (int s = 0; s < 3; ++s) {
                const float negs = s_nred[0][s] + s_nred[1][s]
                                 + s_nred[2][s] + s_nred[3][s];
                const float sxy  = s_obj[s][0];
                const float swh  = s_obj[s][1];
                const float scls = s_obj[s][2];
                const float spos = s_obj[s][3];
                const float scor = s_obj[s][4];
                const float nobj = s_obj[s][5];
                const float Ns = (s == 0) ? (float)(16 * 3 * 6400)
                               : (s == 1) ? (float)(16 * 3 * 1600)
                                          : (float)(16 * 3 * 400);
                const float n_noobj = Ns - nobj;
                const float lxywh = (sxy + swh) / fmaxf(2.f * nobj, 1.f);
                const float lcls  = scls / fmaxf(nobj * (float)NUM_CLASSES, 1.f);
                const float lpos  = spos / fmaxf(nobj, 1.f);
                const float lneg  = (negs + scor) / fmaxf(n_noobj, 1.f);
                const float has   = (nobj > 0.f) ? 1.f : 0.f;
                total += 5.f * lxywh * has + lpos * has + 0.5f * lneg + lcls * has;
            }
            out[0] = total / 3.f;
        }

        // reset flags for the next replay (drained at kernel completion)
        __syncthreads();
        if (tid < OBJ_BLOCKS)
            st_ws(ws + (size_t)tid * 8 + 6, -1.0f);
        else if (tid < OBJ_BLOCKS + NEG_BLOCKS)
            st_ws(ws + NEG_BASE + (tid - OBJ_BLOCKS), -1.0f);
    }
}

extern "C" void kernel_launch(void* const* d_in, const int* in_sizes, int n_in,
                              void* d_out, int out_size, void* d_ws, size_t ws_size,
                              hipStream_t stream) {
    const float* p0  = (const float*)d_in[0];
    const float* p1  = (const float*)d_in[1];
    const float* p2  = (const float*)d_in[2];
    const float* tgt = (const float*)d_in[3];
    float* ws  = (float*)d_ws;   // uses 483 floats
    float* out = (float*)d_out;

    fused_kernel<<<TOTAL_BLOCKS, 256, 0, stream>>>(p0, p1, p2, tgt, ws, out);
}

// Round 12
// 29.553 us; speedup vs baseline: 1.3826x; 1.3826x over previous
//
#include <hip/hip_runtime.h>
#include <math.h>

#define NUM_CLASSES 80
#define OBJ_BLOCKS 1536                 // 3 scales x 16 batch x 32 targets
#define NEG0_BLOCKS 150                 // 76800 float4 / 512 (exact)
#define NEG1_BLOCKS 38                  // ceil(19200 / 512)
#define NEG2_BLOCKS 10                  // ceil(4800 / 512)
#define NEG_BLOCKS (NEG0_BLOCKS + NEG1_BLOCKS + NEG2_BLOCKS)   // 198
#define PRODUCERS (OBJ_BLOCKS + NEG_BLOCKS)                    // 1734
#define NCELLS 21                       // 3 scales x {xy,wh,cls,pos,corr,nobj,neg}

// ---- math helpers (match jax.nn.log_sigmoid / sigmoid in f32) ----
__device__ __forceinline__ float softplusf_(float x) {
    return x > 0.f ? x + log1pf(expf(-x)) : log1pf(expf(x));
}
__device__ __forceinline__ float sigmoidf_(float x) {
    return 1.f / (1.f + expf(-x));
}
// focal_bce(x, t=0) = softplus(x) * sigmoid(x)^2
__device__ __forceinline__ float focal0(float x) {
    float s = sigmoidf_(x);
    return softplusf_(x) * s * s;
}
// focal_bce(x, t=1) = softplus(-x) * sigmoid(-x)^2
__device__ __forceinline__ float focal1(float x) {
    float s = sigmoidf_(-x);
    return softplusf_(-x) * s * s;
}

// ---- device-global accumulators (module .bss: zero at load, never poisoned
// by the harness; the finalizing block resets them to 0 every call ->
// deterministic across graph replays, first call included). One 128B line
// per cell so concurrent atomics hit distinct LLC lines (no serialization).
__device__ float    g_acc[NCELLS][32];   // only [c][0] used
__device__ unsigned g_cnt[8][32];        // striped leaf counters
__device__ unsigned g_master[32];        // cell-last -> master counter

__device__ __forceinline__ float ld_llc(const float* p) {
    return __hip_atomic_load(p, __ATOMIC_RELAXED, __HIP_MEMORY_SCOPE_AGENT);
}
__device__ __forceinline__ void st_llc(float* p, float v) {
    __hip_atomic_store(p, v, __ATOMIC_RELAXED, __HIP_MEMORY_SCOPE_AGENT);
}

// Completion: no fences, no spin, no single hot line (R7: one-line acq_rel
// fetch_add = 73ns/block; R9: agent-release = L2 writeback/block). Producer
// thread0: data atomicAdds -> s_waitcnt vmcnt(0) (own stores only, R10-proven)
// -> relaxed fetch_add on leaf counter (bid&7). Leaf-last bumps master;
// master-last (all 1734 producers' data at LLC by the counter chain)
// finalizes inline.
__device__ __forceinline__ void finish_block(int bid, float* out) {
    asm volatile("s_waitcnt vmcnt(0)" ::: "memory");
    const int k = bid & 7;
    const unsigned expk = (k < 6) ? 217u : 216u;   // 1734 = 6*217 + 2*216
    const unsigned old = __hip_atomic_fetch_add(
        &g_cnt[k][0], 1u, __ATOMIC_RELAXED, __HIP_MEMORY_SCOPE_AGENT);
    if (old != expk - 1u) return;
    const unsigned mold = __hip_atomic_fetch_add(
        &g_master[0], 1u, __ATOMIC_RELAXED, __HIP_MEMORY_SCOPE_AGENT);
    if (mold != 7u) return;

    // ===== global last block: finalize =====
    float a[NCELLS];
    #pragma unroll
    for (int c = 0; c < NCELLS; ++c) a[c] = ld_llc(&g_acc[c][0]);

    float total = 0.f;
    #pragma unroll
    for (int s = 0; s < 3; ++s) {
        const float sxy  = a[s * 7 + 0];
        const float swh  = a[s * 7 + 1];
        const float scls = a[s * 7 + 2];
        const float spos = a[s * 7 + 3];
        const float scor = a[s * 7 + 4];
        const float nobj = a[s * 7 + 5];
        const float negs = a[s * 7 + 6];
        const float Ns = (s == 0) ? (float)(16 * 3 * 6400)
                       : (s == 1) ? (float)(16 * 3 * 1600)
                                  : (float)(16 * 3 * 400);
        const float n_noobj = Ns - nobj;
        const float lxywh = (sxy + swh) / fmaxf(2.f * nobj, 1.f);
        const float lcls  = scls / fmaxf(nobj * (float)NUM_CLASSES, 1.f);
        const float lpos  = spos / fmaxf(nobj, 1.f);
        const float lneg  = (negs + scor) / fmaxf(n_noobj, 1.f);
        const float has   = (nobj > 0.f) ? 1.f : 0.f;
        total += 5.f * lxywh * has + lpos * has + 0.5f * lneg + lcls * has;
    }
    out[0] = total / 3.f;

    // reset for the next call (all producers of THIS call are provably done)
    #pragma unroll
    for (int c = 0; c < NCELLS; ++c) st_llc(&g_acc[c][0], 0.f);
    #pragma unroll
    for (int k2 = 0; k2 < 8; ++k2)
        __hip_atomic_store(&g_cnt[k2][0], 0u, __ATOMIC_RELAXED,
                           __HIP_MEMORY_SCOPE_AGENT);
    __hip_atomic_store(&g_master[0], 0u, __ATOMIC_RELAXED,
                       __HIP_MEMORY_SCOPE_AGENT);
}

template<int NI, int PLANE4>
__device__ __forceinline__ float neg_sum(const float* __restrict__ P,
                                         int lq, int f) {
    float sum = 0.f;
    #pragma unroll
    for (int k = 0; k < 4; ++k) {
        const int idx = lq * 512 + k * 128 + f;
        if (idx < NI) {
            const int plane = idx / PLANE4;          // compile-time divisor
            const int r4 = idx - plane * PLANE4;
            const int b = plane / 3;
            const int a = plane - b * 3;
            const float4 v = *reinterpret_cast<const float4*>(
                P + (size_t)(b * 255 + a * 85 + 4) * (PLANE4 * 4)
                  + (size_t)r4 * 4);
            sum += focal0(v.x) + focal0(v.y) + focal0(v.z) + focal0(v.w);
        }
    }
    return sum;
}

__global__ __launch_bounds__(128)
void fused_kernel(const float* __restrict__ p0,
                  const float* __restrict__ p1,
                  const float* __restrict__ p2,
                  const float* __restrict__ tgt,
                  float* __restrict__ out) {
    __shared__ int   s_cell[32];
    __shared__ int   s_cls[32];
    __shared__ float s_sum[5];
    __shared__ float s_ns[2];

    const int bid = blockIdx.x;
    const int f   = threadIdx.x;          // 128 threads = 2 waves

    if (bid < OBJ_BLOCKS) {
        // ====== object path: one block per (scale, batch, target) ======
        // (R10-proven wide structure: 1 gather/thread = one latency round,
        //  3072 waves of TLP. R11's 48-block consolidation lost that.)
        const int s = bid >> 9;            // /512
        const int r = bid & 511;
        const int b = r >> 5;              // /32
        const int t = r & 31;
        const int H  = (s == 0) ? 80 : (s == 1 ? 40 : 20);
        const int W  = H;
        const int HW = H * W;

        float aw0, aw1, aw2, ah0, ah1, ah2;
        if (s == 0) { aw0=10.f/640.f; aw1=16.f/640.f; aw2=33.f/640.f;
                      ah0=13.f/640.f; ah1=30.f/640.f; ah2=23.f/640.f; }
        else if (s == 1) { aw0=30.f/640.f; aw1=62.f/640.f; aw2=59.f/640.f;
                           ah0=61.f/640.f; ah1=45.f/640.f; ah2=119.f/640.f; }
        else { aw0=116.f/640.f; aw1=156.f/640.f; aw2=373.f/640.f;
               ah0=90.f/640.f;  ah1=198.f/640.f; ah2=326.f/640.f; }

        if (f < 5) s_sum[f] = 0.f;

        if (f < 32) {
            const float* tg = tgt + (size_t)(b * 32 + f) * 5;
            const float w = tg[3], h = tg[4];
            int cell = -1;
            if (w > 0.f && h > 0.f) {
                // argmax IoU over 3 anchors, first-max on ties (strict >)
                float best = -1.f; int ba = 0;
                float inter = fminf(w, aw0) * fminf(h, ah0);
                float iou = inter / (w * h + aw0 * ah0 - inter + 1e-6f);
                if (iou > best) { best = iou; ba = 0; }
                inter = fminf(w, aw1) * fminf(h, ah1);
                iou = inter / (w * h + aw1 * ah1 - inter + 1e-6f);
                if (iou > best) { best = iou; ba = 1; }
                inter = fminf(w, aw2) * fminf(h, ah2);
                iou = inter / (w * h + aw2 * ah2 - inter + 1e-6f);
                if (iou > best) { best = iou; ba = 2; }
                const float xw = tg[1] * (float)W, yh = tg[2] * (float)H;
                int gi = (int)xw; gi = min(max(gi, 0), W - 1); // trunc==astype(i32)
                int gj = (int)yh; gj = min(max(gj, 0), H - 1);
                cell = (ba * H + gj) * W + gi;                 // b uniform in block
            }
            s_cell[f] = cell;
            s_cls[f]  = (int)tg[0];
        }
        __syncthreads();

        const int mycell = s_cell[t];
        bool winner = (mycell >= 0);
        if (winner) {
            // numpy scatter = last-write-wins in t order within the batch
            #pragma unroll 1
            for (int t2 = t + 1; t2 < 32; ++t2)
                if (s_cell[t2] == mycell) { winner = false; break; }
        }
        // `winner` is block-uniform (depends only on bid)

        if (winner) {
            // class UNION over all targets hitting this cell
            unsigned um0 = 0, um1 = 0, um2 = 0;
            #pragma unroll 1
            for (int t2 = 0; t2 < 32; ++t2) {
                if (s_cell[t2] == mycell) {
                    const int c = s_cls[t2];
                    if (c < 32)      um0 |= 1u << c;
                    else if (c < 64) um1 |= 1u << (c - 32);
                    else             um2 |= 1u << (c - 64);
                }
            }

            // geometry of target t (uniform; recomputed by all lanes)
            const float* tg = tgt + (size_t)(b * 32 + t) * 5;
            const float w = tg[3], h = tg[4];
            float best = -1.f; int ba = 0;
            {
                float inter = fminf(w, aw0) * fminf(h, ah0);
                float iou = inter / (w * h + aw0 * ah0 - inter + 1e-6f);
                if (iou > best) { best = iou; ba = 0; }
                inter = fminf(w, aw1) * fminf(h, ah1);
                iou = inter / (w * h + aw1 * ah1 - inter + 1e-6f);
                if (iou > best) { best = iou; ba = 1; }
                inter = fminf(w, aw2) * fminf(h, ah2);
                iou = inter / (w * h + aw2 * ah2 - inter + 1e-6f);
                if (iou > best) { best = iou; ba = 2; }
            }
            const float aw = (ba == 0) ? aw0 : (ba == 1 ? aw1 : aw2);
            const float ah = (ba == 0) ? ah0 : (ba == 1 ? ah1 : ah2);
            const float xw = tg[1] * (float)W, yh = tg[2] * (float)H;
            int gi = (int)xw; gi = min(max(gi, 0), W - 1);
            int gj = (int)yh; gj = min(max(gj, 0), H - 1);

            if (f < 85) {
                const float* P = (s == 0) ? p0 : (s == 1 ? p1 : p2);
                const float val = P[(size_t)(b * 255 + ba * 85 + f) * HW
                                    + (size_t)gj * W + gi];
                float contrib; int cat;
                if (f == 0) {
                    const float d = sigmoidf_(val) - (xw - (float)gi);
                    contrib = d * d; cat = 0;
                } else if (f == 1) {
                    const float d = sigmoidf_(val) - (yh - (float)gj);
                    contrib = d * d; cat = 0;
                } else if (f == 2) {
                    const float e = val - logf(w / aw + 1e-6f);
                    contrib = e * e; cat = 1;
                } else if (f == 3) {
                    const float e = val - logf(h / ah + 1e-6f);
                    contrib = e * e; cat = 1;
                } else if (f == 4) {
                    contrib = focal1(val); cat = 3;
                    atomicAdd(&s_sum[4], -focal0(val)); // correction to all-cell neg
                } else {
                    const int c = f - 5;
                    const bool ts = (c < 32) ? ((um0 >> c) & 1)
                                  : (c < 64) ? ((um1 >> (c - 32)) & 1)
                                             : ((um2 >> (c - 64)) & 1);
                    contrib = ts ? focal1(val) : focal0(val); cat = 2;
                }
                atomicAdd(&s_sum[cat], contrib);
            }
        }
        __syncthreads();
        if (f == 0) {
            if (winner) {
                atomicAdd(&g_acc[s * 7 + 0][0], s_sum[0]);
                atomicAdd(&g_acc[s * 7 + 1][0], s_sum[1]);
                atomicAdd(&g_acc[s * 7 + 2][0], s_sum[2]);
                atomicAdd(&g_acc[s * 7 + 3][0], s_sum[3]);
                atomicAdd(&g_acc[s * 7 + 4][0], s_sum[4]);
                atomicAdd(&g_acc[s * 7 + 5][0], 1.0f);   // n_obj
            }
            finish_block(bid, out);
        }
    } else {
        // ================= all-cell negative path =================
        const int q = bid - OBJ_BLOCKS;              // 0..197
        int s; float sum;
        if (q < NEG0_BLOCKS) {
            s = 0; sum = neg_sum<76800, 1600>(p0, q, f);
        } else if (q < NEG0_BLOCKS + NEG1_BLOCKS) {
            s = 1; sum = neg_sum<19200, 400>(p1, q - NEG0_BLOCKS, f);
        } else {
            s = 2; sum = neg_sum<4800, 100>(p2, q - NEG0_BLOCKS - NEG1_BLOCKS, f);
        }
        #pragma unroll
        for (int off = 32; off; off >>= 1) sum += __shfl_down(sum, off, 64);
        if ((f & 63) == 0) s_ns[f >> 6] = sum;
        __syncthreads();
        if (f == 0) {
            atomicAdd(&g_acc[s * 7 + 6][0], s_ns[0] + s_ns[1]);
            finish_block(bid, out);
        }
    }
}

extern "C" void kernel_launch(void* const* d_in, const int* in_sizes, int n_in,
                              void* d_out, int out_size, void* d_ws, size_t ws_size,
                              hipStream_t stream) {
    const float* p0  = (const float*)d_in[0];
    const float* p1  = (const float*)d_in[1];
    const float* p2  = (const float*)d_in[2];
    const float* tgt = (const float*)d_in[3];
    float* out = (float*)d_out;
    (void)d_ws; (void)ws_size;

    fused_kernel<<<PRODUCERS, 128, 0, stream>>>(p0, p1, p2, tgt, out);
}